// Round 16
// baseline (37.540 us; speedup 1.0000x reference)
//
#include <hip/hip_runtime.h>
#include <cstddef>

#define NUM_TYPE 64
#define DD 256
#define NN 8192
#define GM64 192      // max type-aligned 64-row groups: 8192/64 + 64
#define LSTR 40       // LDS row stride (bf16 elems), +8 pad

typedef __bf16 bf16x8 __attribute__((ext_vector_type(8)));
typedef __bf16 bf16x4 __attribute__((ext_vector_type(4)));
typedef float f32x4 __attribute__((ext_vector_type(4)));

__device__ __forceinline__ bf16x4 cvt4(float4 v) {
  bf16x4 h;
  h[0] = (__bf16)v.x; h[1] = (__bf16)v.y; h[2] = (__bf16)v.z; h[3] = (__bf16)v.w;
  return h;
}

__device__ __forceinline__ float tanh_fast(float x) {
  float xc = fminf(fmaxf(x, -15.f), 15.f);
  float e = __expf(2.f * xc);
  return (e - 1.f) / (e + 1.f);
}

// --- Kernel 1: perm + type-aligned 64-row group table (R15, proven) ------
__global__ __launch_bounds__(1024) void build_perm64(
    const int* __restrict__ bi, int* __restrict__ type_off,
    int* __restrict__ perm, int* __restrict__ gtype, int* __restrict__ gfirst) {
  __shared__ int wcnt[16][NUM_TYPE];
  __shared__ int wbase[16][NUM_TYPE];
  __shared__ int cnt[NUM_TYPE];
  __shared__ int tstart[NUM_TYPE];
  __shared__ int gbase[NUM_TYPE];
  __shared__ int totals[2];
  const int tid = threadIdx.x;
  const int w = tid >> 6;
  for (int i = tid; i < 16 * NUM_TYPE; i += 1024) ((int*)wcnt)[i] = 0;
  __syncthreads();
  int myv[8];
#pragma unroll
  for (int rnd = 0; rnd < 8; ++rnd) {
    int v = bi[rnd * 1024 + tid];
    myv[rnd] = v;
    atomicAdd(&wcnt[w][v], 1);
  }
  __syncthreads();
  if (tid < NUM_TYPE) {
    int s = 0;
#pragma unroll
    for (int ww = 0; ww < 16; ++ww) { wbase[ww][tid] = s; s += wcnt[ww][tid]; }
    cnt[tid] = s;
  }
  __syncthreads();
  if (tid == 0) {
    int s = 0, p = 0;
    for (int t = 0; t < NUM_TYPE; ++t) {
      tstart[t] = s; gbase[t] = p;
      s += cnt[t];
      p += (cnt[t] + 63) >> 6;
    }
    totals[0] = s; totals[1] = p;
  }
  __syncthreads();
  if (tid < NUM_TYPE) {
    const int c = cnt[tid];
    const int ngr = (c + 63) >> 6;
    const int g0 = gbase[tid];
    const int s0 = tstart[tid];
    for (int j = 0; j < ngr; ++j) { gtype[g0 + j] = tid; gfirst[g0 + j] = s0 + j * 64; }
    type_off[tid] = s0;
#pragma unroll
    for (int ww = 0; ww < 16; ++ww) wbase[ww][tid] += s0;
  }
  if (tid == 0) type_off[NUM_TYPE] = totals[0];
  for (int g = totals[1] + tid; g < GM64; g += 1024) gtype[g] = -1;
  __syncthreads();
#pragma unroll
  for (int rnd = 0; rnd < 8; ++rnd) {
    int v = myv[rnd];
    int p = atomicAdd(&wbase[w][v], 1);
    perm[p] = rnd * 1024 + tid;
  }
}

// --- Kernel 2: prep — bf16 convert L/W (linear) + gather desc rows -------
// blocks 0..511: layer1 -> Lp (8192 floats each); 512..527: W -> Wp;
// 528..783: desc rows -> Ap in pad-slot order (1 wave per row, coalesced).
__global__ __launch_bounds__(256) void prep_kernel(
    const float* __restrict__ desc,
    const float* __restrict__ layer1,
    const float* __restrict__ W,
    const int* __restrict__ type_off,
    const int* __restrict__ perm,
    const int* __restrict__ gtype,
    const int* __restrict__ gfirst,
    __bf16* __restrict__ Lp,
    __bf16* __restrict__ Wp,
    __bf16* __restrict__ Ap) {
  const int b = blockIdx.x;
  const int tid = threadIdx.x;
  if (b < 512) {
    const float4* src = reinterpret_cast<const float4*>(layer1);
#pragma unroll
    for (int it = 0; it < 8; ++it) {
      const int idx = b * 2048 + it * 256 + tid;
      *reinterpret_cast<bf16x4*>(Lp + (size_t)idx * 4) = cvt4(src[idx]);
    }
  } else if (b < 528) {
    const float4* src = reinterpret_cast<const float4*>(W);
#pragma unroll
    for (int it = 0; it < 4; ++it) {
      const int idx = (b - 512) * 1024 + it * 256 + tid;
      *reinterpret_cast<bf16x4*>(Wp + (size_t)idx * 4) = cvt4(src[idx]);
    }
  } else {
    const int bb = b - 528;              // 0..255
    const int lane = tid & 63;
    const int wv = tid >> 6;
#pragma unroll
    for (int it = 0; it < 12; ++it) {
      const int slot = bb * 48 + it * 4 + wv;   // 0..12287
      const int g = slot >> 6;
      const int j = slot & 63;
      const int t = gtype[g];
      int src = -1;
      if (t >= 0) {
        const int r = gfirst[g] + j;
        if (r < type_off[t + 1]) src = perm[r];
      }
      bf16x4 h = {};
      if (src >= 0)
        h = cvt4(reinterpret_cast<const float4*>(desc + (size_t)src * DD)[lane]);
      *reinterpret_cast<bf16x4*>(Ap + (size_t)slot * DD + lane * 4) = h;
    }
  }
}

// --- Kernel 3: blocked GEMM 64x64, BK=32 dbuf LDS, all-bf16 staging ------
// Identical schedule to R15; staging loads are bf16x8 (16B/thread/array).
__global__ __launch_bounds__(256) void gemm_tile(
    const __bf16* __restrict__ Ap,
    const __bf16* __restrict__ Lp,
    const __bf16* __restrict__ Wp,
    const float* __restrict__ bias,
    const int* __restrict__ type_off,
    const int* __restrict__ perm,
    const int* __restrict__ gtype,
    const int* __restrict__ gfirst,
    float* __restrict__ out) {
  const int d = blockIdx.x;
  const int l = (d & 7) * 96 + (d >> 3);
  const int g = l >> 2;
  const int cb = l & 3;
  const int t = gtype[g];
  if (t < 0) return;
  const int first = gfirst[g];
  const int limit = type_off[t + 1];

  const int tid = threadIdx.x;
  const int w = tid >> 6;
  const int lane = tid & 63;
  const int l15 = lane & 15;
  const int lg = lane >> 4;
  const int wr = w >> 1;
  const int wc = w & 1;

  __shared__ __bf16 At[2][64][LSTR];
  __shared__ __bf16 Bl[2][64][LSTR];
  __shared__ __bf16 Bw[2][64][LSTR];

  // staging: 4 threads/row, 8 bf16 (16B) each — coalesced 512B rows
  const int srow = tid >> 2;      // 0..63
  const int seg = tid & 3;        // 0..3
  const __bf16* aP  = Ap + ((size_t)g * 64 + srow) * DD + seg * 8;
  const int gcol = cb * 64 + srow;
  const __bf16* blP = Lp + ((size_t)t * DD + gcol) * DD + seg * 8;
  const __bf16* bwP = Wp + (size_t)gcol * DD + seg * 8;

#define STAGE(buf, kb)                                                        \
  {                                                                           \
    *reinterpret_cast<bf16x8*>(&At[buf][srow][seg * 8]) =                     \
        *reinterpret_cast<const bf16x8*>(aP + (kb));                          \
    *reinterpret_cast<bf16x8*>(&Bl[buf][srow][seg * 8]) =                     \
        *reinterpret_cast<const bf16x8*>(blP + (kb));                         \
    *reinterpret_cast<bf16x8*>(&Bw[buf][srow][seg * 8]) =                     \
        *reinterpret_cast<const bf16x8*>(bwP + (kb));                         \
  }

  STAGE(0, 0)
  __syncthreads();

  f32x4 accL[2][2] = {};
  f32x4 accW[2][2] = {};
  int buf = 0;
#pragma unroll
  for (int kc = 0; kc < 8; ++kc) {
    if (kc < 7) STAGE(buf ^ 1, (kc + 1) * 32)
    bf16x8 af[2], bl[2], bw[2];
#pragma unroll
    for (int m = 0; m < 2; ++m)
      af[m] = *reinterpret_cast<const bf16x8*>(&At[buf][wr * 32 + m * 16 + l15][lg * 8]);
#pragma unroll
    for (int n = 0; n < 2; ++n) {
      bl[n] = *reinterpret_cast<const bf16x8*>(&Bl[buf][wc * 32 + n * 16 + l15][lg * 8]);
      bw[n] = *reinterpret_cast<const bf16x8*>(&Bw[buf][wc * 32 + n * 16 + l15][lg * 8]);
    }
#pragma unroll
    for (int m = 0; m < 2; ++m)
#pragma unroll
      for (int n = 0; n < 2; ++n) {
        accL[m][n] = __builtin_amdgcn_mfma_f32_16x16x32_bf16(af[m], bl[n], accL[m][n], 0, 0, 0);
        accW[m][n] = __builtin_amdgcn_mfma_f32_16x16x32_bf16(af[m], bw[n], accW[m][n], 0, 0, 0);
      }
    __syncthreads();
    buf ^= 1;
  }
#undef STAGE

  // epilogue: acc row = lg*4+i within 16-row frag, col = l15
#pragma unroll
  for (int m = 0; m < 2; ++m) {
    const int orow = first + wr * 32 + m * 16 + l15;
    const int sOut = (orow < limit) ? perm[orow] : -1;
#pragma unroll
    for (int i = 0; i < 4; ++i) {
      const int sv = __shfl(sOut, lg * 4 + i, 64);
      if (sv >= 0) {
        float* op = out + (size_t)sv * DD + cb * 64 + wc * 32 + l15;
#pragma unroll
        for (int n = 0; n < 2; ++n) {
          const float bv = bias[cb * 64 + wc * 32 + n * 16 + l15];
          __builtin_nontemporal_store(tanh_fast(accL[m][n][i]) + accW[m][n][i] + bv,
                                      op + n * 16);
        }
      }
    }
  }
}

extern "C" void kernel_launch(void* const* d_in, const int* in_sizes, int n_in,
                              void* d_out, int out_size, void* d_ws, size_t ws_size,
                              hipStream_t stream) {
  const int* bi       = (const int*)d_in[0];
  const float* desc   = (const float*)d_in[1];
  const float* layer1 = (const float*)d_in[2];
  const float* W      = (const float*)d_in[3];
  const float* bias   = (const float*)d_in[4];
  float* out = (float*)d_out;

  char* ws = (char*)d_ws;
  int* type_off = (int*)(ws);                    // 65 ints   @ 0
  int* gtype    = (int*)(ws + 1024);             // 192 ints  @ 1 KB
  int* gfirst   = (int*)(ws + 4096);             // 192 ints  @ 4 KB
  int* perm     = (int*)(ws + 8192);             // 8192 ints @ 8 KB
  __bf16* Ap    = (__bf16*)(ws + 65536);         // 12288*256*2 = 6 MB
  __bf16* Lp    = (__bf16*)(ws + 65536 + 6291456);          // 8 MB
  __bf16* Wp    = (__bf16*)(ws + 65536 + 6291456 + 8388608); // 128 KB

  hipLaunchKernelGGL(build_perm64, dim3(1), dim3(1024), 0, stream,
                     bi, type_off, perm, gtype, gfirst);
  hipLaunchKernelGGL(prep_kernel, dim3(784), dim3(256), 0, stream,
                     desc, layer1, W, type_off, perm, gtype, gfirst, Lp, Wp, Ap);
  hipLaunchKernelGGL(gemm_tile, dim3(GM64 * 4), dim3(256), 0, stream,
                     Ap, Lp, Wp, bias, type_off, perm, gtype, gfirst, out);
}

// Round 17
// 32.501 us; speedup vs baseline: 1.1551x; 1.1551x over previous
//
#include <hip/hip_runtime.h>
#include <cstddef>

#define NUM_TYPE 64
#define DD 256
#define NN 8192
#define GM64 192      // max type-aligned 64-row groups: 8192/64 + 64
#define LSTR 40       // LDS row stride (bf16 elems), +8 pad

typedef __bf16 bf16x8 __attribute__((ext_vector_type(8)));
typedef __bf16 bf16x4 __attribute__((ext_vector_type(4)));
typedef float f32x4 __attribute__((ext_vector_type(4)));

__device__ __forceinline__ bf16x4 cvt4(float4 v) {
  bf16x4 h;
  h[0] = (__bf16)v.x; h[1] = (__bf16)v.y; h[2] = (__bf16)v.z; h[3] = (__bf16)v.w;
  return h;
}

__device__ __forceinline__ float tanh_fast(float x) {
  float xc = fminf(fmaxf(x, -15.f), 15.f);
  float e = __expf(2.f * xc);
  return (e - 1.f) / (e + 1.f);
}

// --- Kernel 1: block 0 = perm + 64-row group table; blocks 1..264 -------
// convert desc (524288 f4) and W (16384 f4) to bf16. 265*?? 264*2048=540672.
__global__ __launch_bounds__(256) void prep_kernel(
    const int* __restrict__ bi,
    const float* __restrict__ desc,
    const float* __restrict__ W,
    int* __restrict__ type_off, int* __restrict__ perm,
    int* __restrict__ gtype, int* __restrict__ gfirst,
    __bf16* __restrict__ descB, __bf16* __restrict__ Wb) {
  const int b = blockIdx.x;
  const int tid = threadIdx.x;
  if (b == 0) {
    __shared__ int wcnt[4][NUM_TYPE];
    __shared__ int wbase[4][NUM_TYPE];
    __shared__ int cnt[NUM_TYPE];
    __shared__ int tstart[NUM_TYPE];
    __shared__ int gbase[NUM_TYPE];
    __shared__ int totals[2];
    const int w = tid >> 6;
    ((int*)wcnt)[tid] = 0;               // 4*64 == 256
    __syncthreads();
#pragma unroll
    for (int r = 0; r < 32; ++r) atomicAdd(&wcnt[w][bi[r * 256 + tid]], 1);
    __syncthreads();
    if (tid < NUM_TYPE) {
      int s = 0;
#pragma unroll
      for (int ww = 0; ww < 4; ++ww) { wbase[ww][tid] = s; s += wcnt[ww][tid]; }
      cnt[tid] = s;
    }
    __syncthreads();
    if (tid == 0) {
      int s = 0, p = 0;
      for (int t = 0; t < NUM_TYPE; ++t) {
        tstart[t] = s; gbase[t] = p;
        s += cnt[t];
        p += (cnt[t] + 63) >> 6;
      }
      totals[0] = s; totals[1] = p;
    }
    __syncthreads();
    if (tid < NUM_TYPE) {
      const int c = cnt[tid];
      const int ngr = (c + 63) >> 6;
      const int g0 = gbase[tid];
      const int s0 = tstart[tid];
      for (int j = 0; j < ngr; ++j) { gtype[g0 + j] = tid; gfirst[g0 + j] = s0 + j * 64; }
      type_off[tid] = s0;
#pragma unroll
      for (int ww = 0; ww < 4; ++ww) wbase[ww][tid] += s0;
    }
    if (tid == 0) type_off[NUM_TYPE] = totals[0];
    for (int g = totals[1] + tid; g < GM64; g += 256) gtype[g] = -1;
    __syncthreads();
#pragma unroll
    for (int r = 0; r < 32; ++r) {
      const int i = r * 256 + tid;
      const int v = bi[i];
      const int p = atomicAdd(&wbase[w][v], 1);
      perm[p] = i;
    }
  } else {
    const float4* srcD = reinterpret_cast<const float4*>(desc);
    const float4* srcW = reinterpret_cast<const float4*>(W);
#pragma unroll
    for (int it = 0; it < 8; ++it) {
      const int idx = (b - 1) * 2048 + it * 256 + tid;
      if (idx < 524288)
        *reinterpret_cast<bf16x4*>(descB + (size_t)idx * 4) = cvt4(srcD[idx]);
      else
        *reinterpret_cast<bf16x4*>(Wb + (size_t)(idx - 524288) * 4) = cvt4(srcW[idx - 524288]);
    }
  }
}

// --- Kernel 2: blocked GEMM 64x64, BK=32 dbuf LDS (R15 schedule) --------
// A and W staged bf16 (1 load each), L staged fp32+cvt (2 loads).
__global__ __launch_bounds__(256) void gemm_tile(
    const __bf16* __restrict__ descB,
    const float* __restrict__ layer1,
    const __bf16* __restrict__ Wb,
    const float* __restrict__ bias,
    const int* __restrict__ type_off,
    const int* __restrict__ perm,
    const int* __restrict__ gtype,
    const int* __restrict__ gfirst,
    float* __restrict__ out) {
  const int d = blockIdx.x;
  const int l = (d & 7) * 96 + (d >> 3);
  const int g = l >> 2;
  const int cb = l & 3;
  const int t = gtype[g];
  if (t < 0) return;
  const int first = gfirst[g];
  const int limit = type_off[t + 1];

  const int tid = threadIdx.x;
  const int w = tid >> 6;
  const int lane = tid & 63;
  const int l15 = lane & 15;
  const int lg = lane >> 4;
  const int wr = w >> 1;
  const int wc = w & 1;

  __shared__ __bf16 At[2][64][LSTR];
  __shared__ __bf16 Bl[2][64][LSTR];
  __shared__ __bf16 Bw[2][64][LSTR];

  // staging: 4 threads/row; A/W: one bf16x8 (16B); L: two float4 + cvt
  const int srow = tid >> 2;      // 0..63
  const int seg = tid & 3;        // 0..3
  const int ar = first + srow;
  const int sA = (ar < limit) ? perm[ar] : -1;
  const __bf16* aP = descB + (size_t)(sA < 0 ? 0 : sA) * DD + seg * 8;
  const int gcol = cb * 64 + srow;
  const float* blP = layer1 + ((size_t)t * DD + gcol) * DD + seg * 8;
  const __bf16* bwP = Wb + (size_t)gcol * DD + seg * 8;

#define STAGE(buf, kb)                                                        \
  {                                                                           \
    bf16x8 av = {};                                                           \
    if (sA >= 0) av = *reinterpret_cast<const bf16x8*>(aP + (kb));            \
    *reinterpret_cast<bf16x8*>(&At[buf][srow][seg * 8]) = av;                 \
    float4 b0 = *reinterpret_cast<const float4*>(blP + (kb));                 \
    float4 b1 = *reinterpret_cast<const float4*>(blP + (kb) + 4);             \
    *reinterpret_cast<bf16x4*>(&Bl[buf][srow][seg * 8])     = cvt4(b0);       \
    *reinterpret_cast<bf16x4*>(&Bl[buf][srow][seg * 8 + 4]) = cvt4(b1);       \
    *reinterpret_cast<bf16x8*>(&Bw[buf][srow][seg * 8]) =                     \
        *reinterpret_cast<const bf16x8*>(bwP + (kb));                         \
  }

  STAGE(0, 0)
  __syncthreads();

  f32x4 accL[2][2] = {};
  f32x4 accW[2][2] = {};
  int buf = 0;
#pragma unroll
  for (int kc = 0; kc < 8; ++kc) {
    if (kc < 7) STAGE(buf ^ 1, (kc + 1) * 32)
    bf16x8 af[2], bl[2], bw[2];
#pragma unroll
    for (int m = 0; m < 2; ++m)
      af[m] = *reinterpret_cast<const bf16x8*>(&At[buf][wr * 32 + m * 16 + l15][lg * 8]);
#pragma unroll
    for (int n = 0; n < 2; ++n) {
      bl[n] = *reinterpret_cast<const bf16x8*>(&Bl[buf][wc * 32 + n * 16 + l15][lg * 8]);
      bw[n] = *reinterpret_cast<const bf16x8*>(&Bw[buf][wc * 32 + n * 16 + l15][lg * 8]);
    }
#pragma unroll
    for (int m = 0; m < 2; ++m)
#pragma unroll
      for (int n = 0; n < 2; ++n) {
        accL[m][n] = __builtin_amdgcn_mfma_f32_16x16x32_bf16(af[m], bl[n], accL[m][n], 0, 0, 0);
        accW[m][n] = __builtin_amdgcn_mfma_f32_16x16x32_bf16(af[m], bw[n], accW[m][n], 0, 0, 0);
      }
    __syncthreads();
    buf ^= 1;
  }
#undef STAGE

  // epilogue: acc row = lg*4+i within 16-row frag, col = l15
#pragma unroll
  for (int m = 0; m < 2; ++m) {
    const int orow = first + wr * 32 + m * 16 + l15;
    const int sOut = (orow < limit) ? perm[orow] : -1;
#pragma unroll
    for (int i = 0; i < 4; ++i) {
      const int sv = __shfl(sOut, lg * 4 + i, 64);
      if (sv >= 0) {
        float* op = out + (size_t)sv * DD + cb * 64 + wc * 32 + l15;
#pragma unroll
        for (int n = 0; n < 2; ++n) {
          const float bv = bias[cb * 64 + wc * 32 + n * 16 + l15];
          __builtin_nontemporal_store(tanh_fast(accL[m][n][i]) + accW[m][n][i] + bv,
                                      op + n * 16);
        }
      }
    }
  }
}

extern "C" void kernel_launch(void* const* d_in, const int* in_sizes, int n_in,
                              void* d_out, int out_size, void* d_ws, size_t ws_size,
                              hipStream_t stream) {
  const int* bi       = (const int*)d_in[0];
  const float* desc   = (const float*)d_in[1];
  const float* layer1 = (const float*)d_in[2];
  const float* W      = (const float*)d_in[3];
  const float* bias   = (const float*)d_in[4];
  float* out = (float*)d_out;

  char* ws = (char*)d_ws;
  int* type_off = (int*)(ws);                    // 65 ints   @ 0
  int* gtype    = (int*)(ws + 1024);             // 192 ints  @ 1 KB
  int* gfirst   = (int*)(ws + 4096);             // 192 ints  @ 4 KB
  int* perm     = (int*)(ws + 8192);             // 8192 ints @ 8 KB
  __bf16* descB = (__bf16*)(ws + 65536);         // 4 MB
  __bf16* Wb    = (__bf16*)(ws + 65536 + 4194304); // 128 KB

  hipLaunchKernelGGL(prep_kernel, dim3(265), dim3(256), 0, stream,
                     bi, desc, W, type_off, perm, gtype, gfirst, descB, Wb);
  hipLaunchKernelGGL(gemm_tile, dim3(GM64 * 4), dim3(256), 0, stream,
                     descB, layer1, Wb, bias, type_off, perm, gtype, gfirst, out);
}

// Round 18
// 25.169 us; speedup vs baseline: 1.4916x; 1.2913x over previous
//
#include <hip/hip_runtime.h>
#include <cstddef>

#define NUM_TYPE 64
#define DD 256
#define NN 8192
#define GM64 192      // max type-aligned 64-row groups: 8192/64 + 64
#define LSTR 40       // LDS row stride (bf16 elems), +8 pad

typedef __bf16 bf16x8 __attribute__((ext_vector_type(8)));
typedef __bf16 bf16x4 __attribute__((ext_vector_type(4)));
typedef float f32x4 __attribute__((ext_vector_type(4)));

__device__ __forceinline__ bf16x4 cvt4(float4 v) {
  bf16x4 h;
  h[0] = (__bf16)v.x; h[1] = (__bf16)v.y; h[2] = (__bf16)v.z; h[3] = (__bf16)v.w;
  return h;
}

__device__ __forceinline__ float tanh_fast(float x) {
  float xc = fminf(fmaxf(x, -15.f), 15.f);
  float e = __expf(2.f * xc);
  return (e - 1.f) / (e + 1.f);
}

// --- Kernel 1: block 0 = R15 perm (1024 thr, 8 rounds); blocks 1..132 ----
// convert desc (524288 f4) + W (16384 f4) -> bf16. 132*4096 = 540672.
__global__ __launch_bounds__(1024) void perm_conv(
    const int* __restrict__ bi,
    const float* __restrict__ desc,
    const float* __restrict__ W,
    int* __restrict__ type_off, int* __restrict__ perm,
    int* __restrict__ gtype, int* __restrict__ gfirst,
    __bf16* __restrict__ descB, __bf16* __restrict__ Wb) {
  const int b = blockIdx.x;
  const int tid = threadIdx.x;
  if (b == 0) {
    __shared__ int wcnt[16][NUM_TYPE];
    __shared__ int wbase[16][NUM_TYPE];
    __shared__ int cnt[NUM_TYPE];
    __shared__ int tstart[NUM_TYPE];
    __shared__ int gbase[NUM_TYPE];
    __shared__ int totals[2];
    const int w = tid >> 6;
    for (int i = tid; i < 16 * NUM_TYPE; i += 1024) ((int*)wcnt)[i] = 0;
    __syncthreads();
    int myv[8];
#pragma unroll
    for (int rnd = 0; rnd < 8; ++rnd) {
      int v = bi[rnd * 1024 + tid];
      myv[rnd] = v;
      atomicAdd(&wcnt[w][v], 1);
    }
    __syncthreads();
    if (tid < NUM_TYPE) {
      int s = 0;
#pragma unroll
      for (int ww = 0; ww < 16; ++ww) { wbase[ww][tid] = s; s += wcnt[ww][tid]; }
      cnt[tid] = s;
    }
    __syncthreads();
    if (tid == 0) {
      int s = 0, p = 0;
      for (int t = 0; t < NUM_TYPE; ++t) {
        tstart[t] = s; gbase[t] = p;
        s += cnt[t];
        p += (cnt[t] + 63) >> 6;
      }
      totals[0] = s; totals[1] = p;
    }
    __syncthreads();
    if (tid < NUM_TYPE) {
      const int c = cnt[tid];
      const int ngr = (c + 63) >> 6;
      const int g0 = gbase[tid];
      const int s0 = tstart[tid];
      for (int j = 0; j < ngr; ++j) { gtype[g0 + j] = tid; gfirst[g0 + j] = s0 + j * 64; }
      type_off[tid] = s0;
#pragma unroll
      for (int ww = 0; ww < 16; ++ww) wbase[ww][tid] += s0;
    }
    if (tid == 0) type_off[NUM_TYPE] = totals[0];
    for (int g = totals[1] + tid; g < GM64; g += 1024) gtype[g] = -1;
    __syncthreads();
#pragma unroll
    for (int rnd = 0; rnd < 8; ++rnd) {
      int v = myv[rnd];
      int p = atomicAdd(&wbase[w][v], 1);
      perm[p] = rnd * 1024 + tid;
    }
  } else {
    const float4* srcD = reinterpret_cast<const float4*>(desc);
    const float4* srcW = reinterpret_cast<const float4*>(W);
#pragma unroll
    for (int it = 0; it < 4; ++it) {
      const int idx = (b - 1) * 4096 + it * 1024 + tid;
      if (idx < 524288)
        *reinterpret_cast<bf16x4*>(descB + (size_t)idx * 4) = cvt4(srcD[idx]);
      else
        *reinterpret_cast<bf16x4*>(Wb + (size_t)(idx - 524288) * 4) = cvt4(srcW[idx - 524288]);
    }
  }
}

// --- Kernel 2: blocked GEMM 64x64, BK=32 dbuf LDS (R17 gemm, unchanged) --
__global__ __launch_bounds__(256) void gemm_tile(
    const __bf16* __restrict__ descB,
    const float* __restrict__ layer1,
    const __bf16* __restrict__ Wb,
    const float* __restrict__ bias,
    const int* __restrict__ type_off,
    const int* __restrict__ perm,
    const int* __restrict__ gtype,
    const int* __restrict__ gfirst,
    float* __restrict__ out) {
  const int d = blockIdx.x;
  const int l = (d & 7) * 96 + (d >> 3);
  const int g = l >> 2;
  const int cb = l & 3;
  const int t = gtype[g];
  if (t < 0) return;
  const int first = gfirst[g];
  const int limit = type_off[t + 1];

  const int tid = threadIdx.x;
  const int w = tid >> 6;
  const int lane = tid & 63;
  const int l15 = lane & 15;
  const int lg = lane >> 4;
  const int wr = w >> 1;
  const int wc = w & 1;

  __shared__ __bf16 At[2][64][LSTR];
  __shared__ __bf16 Bl[2][64][LSTR];
  __shared__ __bf16 Bw[2][64][LSTR];

  const int srow = tid >> 2;      // 0..63
  const int seg = tid & 3;        // 0..3
  const int ar = first + srow;
  const int sA = (ar < limit) ? perm[ar] : -1;
  const __bf16* aP = descB + (size_t)(sA < 0 ? 0 : sA) * DD + seg * 8;
  const int gcol = cb * 64 + srow;
  const float* blP = layer1 + ((size_t)t * DD + gcol) * DD + seg * 8;
  const __bf16* bwP = Wb + (size_t)gcol * DD + seg * 8;

#define STAGE(buf, kb)                                                        \
  {                                                                           \
    bf16x8 av = {};                                                           \
    if (sA >= 0) av = *reinterpret_cast<const bf16x8*>(aP + (kb));            \
    *reinterpret_cast<bf16x8*>(&At[buf][srow][seg * 8]) = av;                 \
    float4 b0 = *reinterpret_cast<const float4*>(blP + (kb));                 \
    float4 b1 = *reinterpret_cast<const float4*>(blP + (kb) + 4);             \
    *reinterpret_cast<bf16x4*>(&Bl[buf][srow][seg * 8])     = cvt4(b0);       \
    *reinterpret_cast<bf16x4*>(&Bl[buf][srow][seg * 8 + 4]) = cvt4(b1);       \
    *reinterpret_cast<bf16x8*>(&Bw[buf][srow][seg * 8]) =                     \
        *reinterpret_cast<const bf16x8*>(bwP + (kb));                         \
  }

  STAGE(0, 0)
  __syncthreads();

  f32x4 accL[2][2] = {};
  f32x4 accW[2][2] = {};
  int buf = 0;
#pragma unroll
  for (int kc = 0; kc < 8; ++kc) {
    if (kc < 7) STAGE(buf ^ 1, (kc + 1) * 32)
    bf16x8 af[2], bl[2], bw[2];
#pragma unroll
    for (int m = 0; m < 2; ++m)
      af[m] = *reinterpret_cast<const bf16x8*>(&At[buf][wr * 32 + m * 16 + l15][lg * 8]);
#pragma unroll
    for (int n = 0; n < 2; ++n) {
      bl[n] = *reinterpret_cast<const bf16x8*>(&Bl[buf][wc * 32 + n * 16 + l15][lg * 8]);
      bw[n] = *reinterpret_cast<const bf16x8*>(&Bw[buf][wc * 32 + n * 16 + l15][lg * 8]);
    }
#pragma unroll
    for (int m = 0; m < 2; ++m)
#pragma unroll
      for (int n = 0; n < 2; ++n) {
        accL[m][n] = __builtin_amdgcn_mfma_f32_16x16x32_bf16(af[m], bl[n], accL[m][n], 0, 0, 0);
        accW[m][n] = __builtin_amdgcn_mfma_f32_16x16x32_bf16(af[m], bw[n], accW[m][n], 0, 0, 0);
      }
    __syncthreads();
    buf ^= 1;
  }
#undef STAGE

#pragma unroll
  for (int m = 0; m < 2; ++m) {
    const int orow = first + wr * 32 + m * 16 + l15;
    const int sOut = (orow < limit) ? perm[orow] : -1;
#pragma unroll
    for (int i = 0; i < 4; ++i) {
      const int sv = __shfl(sOut, lg * 4 + i, 64);
      if (sv >= 0) {
        float* op = out + (size_t)sv * DD + cb * 64 + wc * 32 + l15;
#pragma unroll
        for (int n = 0; n < 2; ++n) {
          const float bv = bias[cb * 64 + wc * 32 + n * 16 + l15];
          __builtin_nontemporal_store(tanh_fast(accL[m][n][i]) + accW[m][n][i] + bv,
                                      op + n * 16);
        }
      }
    }
  }
}

extern "C" void kernel_launch(void* const* d_in, const int* in_sizes, int n_in,
                              void* d_out, int out_size, void* d_ws, size_t ws_size,
                              hipStream_t stream) {
  const int* bi       = (const int*)d_in[0];
  const float* desc   = (const float*)d_in[1];
  const float* layer1 = (const float*)d_in[2];
  const float* W      = (const float*)d_in[3];
  const float* bias   = (const float*)d_in[4];
  float* out = (float*)d_out;

  char* ws = (char*)d_ws;
  int* type_off = (int*)(ws);                    // 65 ints   @ 0
  int* gtype    = (int*)(ws + 1024);             // 192 ints  @ 1 KB
  int* gfirst   = (int*)(ws + 4096);             // 192 ints  @ 4 KB
  int* perm     = (int*)(ws + 8192);             // 8192 ints @ 8 KB
  __bf16* descB = (__bf16*)(ws + 65536);         // 4 MB
  __bf16* Wb    = (__bf16*)(ws + 65536 + 4194304); // 128 KB

  hipLaunchKernelGGL(perm_conv, dim3(133), dim3(1024), 0, stream,
                     bi, desc, W, type_off, perm, gtype, gfirst, descB, Wb);
  hipLaunchKernelGGL(gemm_tile, dim3(GM64 * 4), dim3(256), 0, stream,
                     descB, layer1, Wb, bias, type_off, perm, gtype, gfirst, out);
}